// Round 10
// baseline (312.516 us; speedup 1.0000x reference)
//
#include <hip/hip_runtime.h>
#include <stdint.h>

// Problem shape (fixed by reference setup_inputs): B=4096, L=2048.
#define LROW 2048
#define THREADS 256
#define NBINS 1024
#define BPT (NBINS / THREADS)   // 4 bins owned per thread

__device__ __forceinline__ int swz(int b) {
    return ((b & (BPT - 1)) << 8) + (b >> 2);
}

// ---------------- FULL KERNEL (round-9, unchanged, correct) ----------------
__global__ __launch_bounds__(THREADS) void time_greedy_rank_kernel(
    const float* __restrict__ time,
    const int* __restrict__ mask,
    const int* __restrict__ pad_value_p,
    int* __restrict__ pred,
    int* __restrict__ valid_out)
{
    __shared__ uint64_t keys[LROW];
    __shared__ uint32_t hstart[NBINS];
    __shared__ uint32_t hpos[NBINS];
    __shared__ uint32_t wsum[4];

    const int row = blockIdx.x;
    const int tid = threadIdx.x;
    const int lane = tid & 63;
    const int wid = tid >> 6;

#pragma unroll
    for (int e = 0; e < BPT; ++e) hpos[tid + e * THREADS] = 0;
    __syncthreads();

    const float4* trow4 = (const float4*)(time + (size_t)row * LROW);
    const int4*   mrow4 = (const int4*)(mask + (size_t)row * LROW);

    uint32_t ukey[8];
    int      bkt[8];
    int      mval[8];
#pragma unroll
    for (int c = 0; c < 2; ++c) {
        const int v = tid + c * THREADS;
        const float4 tq = trow4[v];
        const int4   mq = mrow4[v];
        const float tf[4] = {tq.x, tq.y, tq.z, tq.w};
        const int   mf[4] = {mq.x, mq.y, mq.z, mq.w};
#pragma unroll
        for (int j = 0; j < 4; ++j) {
            const int e = c * 4 + j;
            const uint32_t fb = __float_as_uint(tf[j]);
            ukey[e] = fb ^ ((uint32_t)((int32_t)fb >> 31) | 0x80000000u);
            int b = (int)(tf[j] * (float)NBINS);
            b = (b < 0) ? 0 : ((b > NBINS - 1) ? NBINS - 1 : b);
            bkt[e] = b;
            mval[e] = mf[j];
            if (!mf[j]) atomicAdd(&hpos[swz(b)], 1u);
        }
    }
    __syncthreads();

    uint32_t h[BPT];
    uint32_t lsum = 0;
#pragma unroll
    for (int e = 0; e < BPT; ++e) {
        h[e] = hpos[e * THREADS + tid];
        lsum += h[e];
    }
    uint32_t incl = lsum;
#pragma unroll
    for (int off = 1; off < 64; off <<= 1) {
        const uint32_t y = __shfl_up(incl, off, 64);
        if (lane >= off) incl += y;
    }
    if (lane == 63) wsum[wid] = incl;
    __syncthreads();
    uint32_t woff = 0, total = 0;
#pragma unroll
    for (int w = 0; w < 4; ++w) {
        const uint32_t s = wsum[w];
        if (w < wid) woff += s;
        total += s;
    }
    uint32_t run = woff + incl - lsum;
#pragma unroll
    for (int e = 0; e < BPT; ++e) {
        hstart[e * THREADS + tid] = run;
        hpos[e * THREADS + tid] = run;
        run += h[e];
    }
    __syncthreads();

#pragma unroll
    for (int c = 0; c < 2; ++c) {
#pragma unroll
        for (int j = 0; j < 4; ++j) {
            const int e = c * 4 + j;
            if (!mval[e]) {
                const int i = 4 * tid + c * (4 * THREADS) + j;
                const uint32_t pos = atomicAdd(&hpos[swz(bkt[e])], 1u);
                keys[pos] = ((uint64_t)ukey[e] << 32) | (uint32_t)i;
            }
        }
    }
    __syncthreads();

    const int vld = (int)total;
    const int pad = pad_value_p[0];
    int* prow = pred + (size_t)row * LROW;
#pragma unroll
    for (int c = 0; c < 2; ++c) {
#pragma unroll
        for (int j = 0; j < 4; ++j) {
            const int e = c * 4 + j;
            if (!mval[e]) {
                const int i = 4 * tid + c * (4 * THREADS) + j;
                const uint64_t my = ((uint64_t)ukey[e] << 32) | (uint32_t)i;
                const int sb = swz(bkt[e]);
                const uint32_t s = hstart[sb];
                const uint32_t en = hpos[sb];
                uint32_t rank = 0;
                for (uint32_t q = s; q < en; ++q)
                    rank += (keys[q] < my) ? 1u : 0u;
                prow[s + rank] = i;
            }
        }
    }

    for (int i = vld + tid; i < LROW; i += THREADS) prow[i] = pad;
    if (tid == 0) valid_out[row] = vld;
}

// ---------------- DIAGNOSTIC PROBES (write only to d_ws) ----------------
// All probes carry the full kernel's LDS footprint so occupancy matches
// (6 blocks/CU). Rows are rotated per iteration so loads are genuine.

__global__ __launch_bounds__(THREADS) void probe_load_x10(
    const float* __restrict__ time, const int* __restrict__ mask,
    uint32_t* __restrict__ ws, size_t ws_words, int bmask)
{
    __shared__ uint64_t keys[LROW];
    __shared__ uint32_t hstart[NBINS];
    __shared__ uint32_t hpos[NBINS];
    __shared__ uint32_t wsum[4];
    const int tid = threadIdx.x;
    uint32_t acc = 0;
    for (int r = 0; r < 10; ++r) {
        const int row = (blockIdx.x + r * 511) & bmask;
        const float4* trow4 = (const float4*)(time + (size_t)row * LROW);
        const int4*   mrow4 = (const int4*)(mask + (size_t)row * LROW);
#pragma unroll
        for (int c = 0; c < 2; ++c) {
            const int v = tid + c * THREADS;
            const float4 tq = trow4[v];
            const int4   mq = mrow4[v];
            const float tf[4] = {tq.x, tq.y, tq.z, tq.w};
            const int   mf[4] = {mq.x, mq.y, mq.z, mq.w};
#pragma unroll
            for (int j = 0; j < 4; ++j) {
                const uint32_t fb = __float_as_uint(tf[j]);
                const uint32_t uk = fb ^ ((uint32_t)((int32_t)fb >> 31) | 0x80000000u);
                int b = (int)(tf[j] * (float)NBINS);
                b = (b < 0) ? 0 : ((b > NBINS - 1) ? NBINS - 1 : b);
                acc ^= uk + (uint32_t)(b * (mf[j] + 1));
            }
        }
    }
    keys[tid] = acc; hstart[tid] = acc; hpos[tid] = acc;
    if (tid < 4) wsum[tid] = acc;
    __syncthreads();
    acc ^= (uint32_t)keys[(tid + 7) & 255] ^ hstart[(tid + 3) & 255]
         ^ hpos[(tid + 5) & 255] ^ wsum[tid & 3];
    const size_t w = (size_t)blockIdx.x * THREADS + tid;
    if (w < ws_words) ws[w] = acc;
}

__global__ __launch_bounds__(THREADS) void probe_front_x5(
    const float* __restrict__ time, const int* __restrict__ mask,
    uint32_t* __restrict__ ws, size_t ws_words, int bmask)
{
    __shared__ uint64_t keys[LROW];
    __shared__ uint32_t hstart[NBINS];
    __shared__ uint32_t hpos[NBINS];
    __shared__ uint32_t wsum[4];
    const int tid = threadIdx.x;
    const int lane = tid & 63;
    const int wid = tid >> 6;
    uint32_t acc = 0;
    for (int r = 0; r < 5; ++r) {
        const int row = (blockIdx.x + r * 511) & bmask;
#pragma unroll
        for (int e = 0; e < BPT; ++e) hpos[tid + e * THREADS] = 0;
        __syncthreads();
        const float4* trow4 = (const float4*)(time + (size_t)row * LROW);
        const int4*   mrow4 = (const int4*)(mask + (size_t)row * LROW);
#pragma unroll
        for (int c = 0; c < 2; ++c) {
            const int v = tid + c * THREADS;
            const float4 tq = trow4[v];
            const int4   mq = mrow4[v];
            const float tf[4] = {tq.x, tq.y, tq.z, tq.w};
            const int   mf[4] = {mq.x, mq.y, mq.z, mq.w};
#pragma unroll
            for (int j = 0; j < 4; ++j) {
                int b = (int)(tf[j] * (float)NBINS);
                b = (b < 0) ? 0 : ((b > NBINS - 1) ? NBINS - 1 : b);
                if (!mf[j]) atomicAdd(&hpos[swz(b)], 1u);
            }
        }
        __syncthreads();
        uint32_t h[BPT];
        uint32_t lsum = 0;
#pragma unroll
        for (int e = 0; e < BPT; ++e) {
            h[e] = hpos[e * THREADS + tid];
            lsum += h[e];
        }
        uint32_t incl = lsum;
#pragma unroll
        for (int off = 1; off < 64; off <<= 1) {
            const uint32_t y = __shfl_up(incl, off, 64);
            if (lane >= off) incl += y;
        }
        if (lane == 63) wsum[wid] = incl;
        __syncthreads();
        uint32_t woff = 0, total = 0;
#pragma unroll
        for (int w = 0; w < 4; ++w) {
            const uint32_t s = wsum[w];
            if (w < wid) woff += s;
            total += s;
        }
        uint32_t run = woff + incl - lsum;
#pragma unroll
        for (int e = 0; e < BPT; ++e) { acc ^= run; run += h[e]; }
        acc ^= total;
        __syncthreads();   // protect hpos/wsum reuse next iteration
    }
    keys[tid] = acc; hstart[tid] = acc;
    __syncthreads();
    acc ^= (uint32_t)keys[(tid + 7) & 255] ^ hstart[(tid + 3) & 255];
    const size_t w = (size_t)blockIdx.x * THREADS + tid;
    if (w < ws_words) ws[w] = acc;
}

__global__ __launch_bounds__(THREADS) void probe_scatter_x5(
    const float* __restrict__ time, const int* __restrict__ mask,
    uint32_t* __restrict__ ws, size_t ws_words, int bmask)
{
    __shared__ uint64_t keys[LROW];
    __shared__ uint32_t hstart[NBINS];
    __shared__ uint32_t hpos[NBINS];
    __shared__ uint32_t wsum[4];
    const int tid = threadIdx.x;
    const int lane = tid & 63;
    const int wid = tid >> 6;
    uint32_t acc = 0;
    for (int r = 0; r < 5; ++r) {
        const int row = (blockIdx.x + r * 511) & bmask;
#pragma unroll
        for (int e = 0; e < BPT; ++e) hpos[tid + e * THREADS] = 0;
        __syncthreads();
        const float4* trow4 = (const float4*)(time + (size_t)row * LROW);
        const int4*   mrow4 = (const int4*)(mask + (size_t)row * LROW);
        uint32_t ukey[8];
        int      bkt[8];
        int      mval[8];
#pragma unroll
        for (int c = 0; c < 2; ++c) {
            const int v = tid + c * THREADS;
            const float4 tq = trow4[v];
            const int4   mq = mrow4[v];
            const float tf[4] = {tq.x, tq.y, tq.z, tq.w};
            const int   mf[4] = {mq.x, mq.y, mq.z, mq.w};
#pragma unroll
            for (int j = 0; j < 4; ++j) {
                const int e = c * 4 + j;
                const uint32_t fb = __float_as_uint(tf[j]);
                ukey[e] = fb ^ ((uint32_t)((int32_t)fb >> 31) | 0x80000000u);
                int b = (int)(tf[j] * (float)NBINS);
                b = (b < 0) ? 0 : ((b > NBINS - 1) ? NBINS - 1 : b);
                bkt[e] = b;
                mval[e] = mf[j];
                if (!mf[j]) atomicAdd(&hpos[swz(b)], 1u);
            }
        }
        __syncthreads();
        uint32_t h[BPT];
        uint32_t lsum = 0;
#pragma unroll
        for (int e = 0; e < BPT; ++e) {
            h[e] = hpos[e * THREADS + tid];
            lsum += h[e];
        }
        uint32_t incl = lsum;
#pragma unroll
        for (int off = 1; off < 64; off <<= 1) {
            const uint32_t y = __shfl_up(incl, off, 64);
            if (lane >= off) incl += y;
        }
        if (lane == 63) wsum[wid] = incl;
        __syncthreads();
        uint32_t woff = 0, total = 0;
#pragma unroll
        for (int w = 0; w < 4; ++w) {
            const uint32_t s = wsum[w];
            if (w < wid) woff += s;
            total += s;
        }
        uint32_t run = woff + incl - lsum;
#pragma unroll
        for (int e = 0; e < BPT; ++e) {
            hstart[e * THREADS + tid] = run;
            hpos[e * THREADS + tid] = run;
            run += h[e];
        }
        __syncthreads();
#pragma unroll
        for (int c = 0; c < 2; ++c) {
#pragma unroll
            for (int j = 0; j < 4; ++j) {
                const int e = c * 4 + j;
                if (!mval[e]) {
                    const int i = 4 * tid + c * (4 * THREADS) + j;
                    const uint32_t pos = atomicAdd(&hpos[swz(bkt[e])], 1u);
                    keys[pos] = ((uint64_t)ukey[e] << 32) | (uint32_t)i;
                }
            }
        }
        __syncthreads();
        acc ^= (uint32_t)keys[(8 * tid + r * 13) & (LROW - 1)] ^ total;
        __syncthreads();   // protect keys/hpos reuse next iteration
    }
    const size_t w = (size_t)blockIdx.x * THREADS + tid;
    if (w < ws_words) ws[w] = acc;
}

extern "C" void kernel_launch(void* const* d_in, const int* in_sizes, int n_in,
                              void* d_out, int out_size, void* d_ws, size_t ws_size,
                              hipStream_t stream) {
    const float* time = (const float*)d_in[0];
    const int* mask = (const int*)d_in[1];
    const int* pad_value = (const int*)d_in[2];

    const int B = in_sizes[0] / LROW;
    const int bmask = B - 1;   // B = 4096, power of two

    int* pred = (int*)d_out;
    int* valid_out = pred + (size_t)B * LROW;

    // Correct output first.
    time_greedy_rank_kernel<<<B, THREADS, 0, stream>>>(time, mask, pad_value,
                                                       pred, valid_out);

    // Diagnostic probes (scratch only; this round is sacrificial for timing).
    uint32_t* ws = (uint32_t*)d_ws;
    const size_t ws_words = ws_size / 4;
    probe_load_x10<<<B, THREADS, 0, stream>>>(time, mask, ws, ws_words, bmask);
    probe_front_x5<<<B, THREADS, 0, stream>>>(time, mask, ws, ws_words, bmask);
    probe_scatter_x5<<<B, THREADS, 0, stream>>>(time, mask, ws, ws_words, bmask);
}

// Round 11
// 113.708 us; speedup vs baseline: 2.7484x; 2.7484x over previous
//
#include <hip/hip_runtime.h>
#include <stdint.h>

// Problem shape (fixed by reference setup_inputs): B=4096, L=2048.
#define LROW 2048
#define THREADS 256
#define NBINS 1024
#define BPT (NBINS / THREADS)   // 4 bins owned per thread

// Transposed hist layout: bin b -> [(b&3)*256 + (b>>2)] so thread-contiguous
// bin ownership is lane-stride-1 (fixed 16-way conflicts, round 8).
__device__ __forceinline__ int swz(int b) {
    return ((b & (BPT - 1)) << 8) + (b >> 2);
}

// One block per row. Stable argsort of (masked -> +inf) keys; masked elements
// DROPPED (outputs past `valid` are pad). Pipeline:
//   1. load + histogram (monotone bucket fn floor(t*1024))
//   2. scan -> bucket starts
//   3. scatter composite keys (sortable_bits<<32)|idx into bucket ranges
//   4. elements-parallel RANK within bucket (independent LDS reads; round-10
//      probes showed r8's insertion sort was dependent-chain latency-bound)
//      writing u16 ranks into an LDS staging array that ALIASES hpos (dead
//      after scatter; bucket end comes from hstart[b+1] / total)
//   5. coalesced int4 emit with pad folded in (round-10 showed r9's scattered
//      4B global stores were the other ~23us back-half; fills run 6.4 TB/s)
// Composite keys all-distinct; ties in t break by lower index == stable
// argsort == reference argmin semantics.
//
// mask (jnp.bool_) is uploaded by the harness as int32.
__global__ __launch_bounds__(THREADS) void time_greedy_rank_kernel(
    const float* __restrict__ time,
    const int* __restrict__ mask,             // int32: nonzero = excluded
    const int* __restrict__ pad_value_p,
    int* __restrict__ pred,                   // [B, L] int32
    int* __restrict__ valid_out)              // [B]    int32
{
    __shared__ uint64_t keys[LROW];      // 16 KB: scattered composite keys
    __shared__ uint32_t hstart[NBINS];   // 4 KB: exclusive bucket starts (preserved)
    __shared__ uint32_t hpos[NBINS];     // 4 KB: counts->pos; REUSED as u16 oidx
    __shared__ uint32_t wsum[4];

    uint16_t* oidx = (uint16_t*)hpos;    // aliases hpos after scatter is done

    const int row = blockIdx.x;
    const int tid = threadIdx.x;
    const int lane = tid & 63;
    const int wid = tid >> 6;

    // ---- init hpos (stride-1) ----
#pragma unroll
    for (int e = 0; e < BPT; ++e) hpos[tid + e * THREADS] = 0;
    __syncthreads();

    // ---- vectorized load + histogram of valid elements ----
    const float4* trow4 = (const float4*)(time + (size_t)row * LROW);
    const int4*   mrow4 = (const int4*)(mask + (size_t)row * LROW);

    uint32_t ukey[8];
    int      bkt[8];
    int      mval[8];
#pragma unroll
    for (int c = 0; c < 2; ++c) {
        const int v = tid + c * THREADS;
        const float4 tq = trow4[v];
        const int4   mq = mrow4[v];
        const float tf[4] = {tq.x, tq.y, tq.z, tq.w};
        const int   mf[4] = {mq.x, mq.y, mq.z, mq.w};
#pragma unroll
        for (int j = 0; j < 4; ++j) {
            const int e = c * 4 + j;
            const uint32_t fb = __float_as_uint(tf[j]);
            // order-preserving float->uint transform (general form)
            ukey[e] = fb ^ ((uint32_t)((int32_t)fb >> 31) | 0x80000000u);
            int b = (int)(tf[j] * (float)NBINS);   // monotone value bucketing
            b = (b < 0) ? 0 : ((b > NBINS - 1) ? NBINS - 1 : b);
            bkt[e] = b;
            mval[e] = mf[j];
            if (!mf[j]) atomicAdd(&hpos[swz(b)], 1u);
        }
    }
    __syncthreads();

    // ---- exclusive prefix sum over 1024 bins (thread t owns bins 4t..4t+3) ----
    uint32_t h[BPT];
    uint32_t lsum = 0;
#pragma unroll
    for (int e = 0; e < BPT; ++e) {
        h[e] = hpos[e * THREADS + tid];   // stride-1
        lsum += h[e];
    }
    uint32_t incl = lsum;                 // wave-inclusive scan
#pragma unroll
    for (int off = 1; off < 64; off <<= 1) {
        const uint32_t y = __shfl_up(incl, off, 64);
        if (lane >= off) incl += y;
    }
    if (lane == 63) wsum[wid] = incl;
    __syncthreads();
    uint32_t woff = 0, total = 0;
#pragma unroll
    for (int w = 0; w < 4; ++w) {
        const uint32_t s = wsum[w];
        if (w < wid) woff += s;
        total += s;
    }
    uint32_t run = woff + incl - lsum;    // exclusive prefix for this thread's bins
#pragma unroll
    for (int e = 0; e < BPT; ++e) {
        hstart[e * THREADS + tid] = run;  // preserved exclusive start
        hpos[e * THREADS + tid] = run;    // running position for scatter
        run += h[e];
    }
    __syncthreads();

    // ---- scatter valid elements into their bucket ranges ----
#pragma unroll
    for (int c = 0; c < 2; ++c) {
#pragma unroll
        for (int j = 0; j < 4; ++j) {
            const int e = c * 4 + j;
            if (!mval[e]) {
                const int i = 4 * tid + c * (4 * THREADS) + j;  // element index
                const uint32_t pos = atomicAdd(&hpos[swz(bkt[e])], 1u);
                keys[pos] = ((uint64_t)ukey[e] << 32) | (uint32_t)i;
            }
        }
    }
    __syncthreads();
    // hpos is now DEAD (bucket end b == hstart[b+1], or total for the last).
    // Its 4 KB are reused as the u16 rank-staging array oidx.

    // ---- elements-parallel rank -> u16 LDS staging ----
    const int vld = (int)total;
#pragma unroll
    for (int c = 0; c < 2; ++c) {
#pragma unroll
        for (int j = 0; j < 4; ++j) {
            const int e = c * 4 + j;
            if (!mval[e]) {
                const int i = 4 * tid + c * (4 * THREADS) + j;
                const uint64_t my = ((uint64_t)ukey[e] << 32) | (uint32_t)i;
                const int b = bkt[e];
                const uint32_t s = hstart[swz(b)];
                const uint32_t en = (b == NBINS - 1) ? (uint32_t)vld
                                                     : hstart[swz(b + 1)];
                uint32_t rank = 0;
                for (uint32_t q = s; q < en; ++q)
                    rank += (keys[q] < my) ? 1u : 0u;   // excludes self (==)
                oidx[s + rank] = (uint16_t)i;   // scattered u16 LDS write
            }
        }
    }
    __syncthreads();

    // ---- coalesced int4 emit, pad folded in ----
    const int pad = pad_value_p[0];
    int4* prow4 = (int4*)(pred + (size_t)row * LROW);
#pragma unroll
    for (int c = 0; c < 2; ++c) {
        const int v = tid + c * THREADS;
        const int base = 4 * v;
        int4 o;                              // 8B/lane u16 reads: 2-way, free
        o.x = (base + 0 < vld) ? (int)oidx[base + 0] : pad;
        o.y = (base + 1 < vld) ? (int)oidx[base + 1] : pad;
        o.z = (base + 2 < vld) ? (int)oidx[base + 2] : pad;
        o.w = (base + 3 < vld) ? (int)oidx[base + 3] : pad;
        prow4[v] = o;                        // 1 KB/wave coalesced store
    }
    if (tid == 0) valid_out[row] = vld;
}

extern "C" void kernel_launch(void* const* d_in, const int* in_sizes, int n_in,
                              void* d_out, int out_size, void* d_ws, size_t ws_size,
                              hipStream_t stream) {
    const float* time = (const float*)d_in[0];
    const int* mask = (const int*)d_in[1];
    const int* pad_value = (const int*)d_in[2];

    const int B = in_sizes[0] / LROW;

    // d_out layout: pred [B*L] int32, then valid [B] int32 (tuple concat order)
    int* pred = (int*)d_out;
    int* valid_out = pred + (size_t)B * LROW;

    time_greedy_rank_kernel<<<B, THREADS, 0, stream>>>(time, mask, pad_value,
                                                       pred, valid_out);
}

// Round 12
// 113.215 us; speedup vs baseline: 2.7604x; 1.0044x over previous
//
#include <hip/hip_runtime.h>
#include <stdint.h>

// Problem shape (fixed by reference setup_inputs): B=4096, L=2048.
#define LROW 2048
#define THREADS 256
#define NBINS 1024
#define BPT (NBINS / THREADS)   // 4 bins owned per thread
#define RUNROLL 6               // fixed predicated rank unroll; P(size>6)~6e-4

// Transposed hist layout: bin b -> [(b&3)*256 + (b>>2)] so thread-contiguous
// bin ownership is lane-stride-1 in the scan (fixed 16-way conflicts, r8).
__device__ __forceinline__ int swz(int b) {
    return ((b & (BPT - 1)) << 8) + (b >> 2);
}

// One block per row. Stable argsort of (masked -> +inf) keys; masked elements
// DROPPED (outputs past `valid` are pad). Pipeline:
//   1. load + histogram (monotone bucket fn floor(t*1024))
//   2. scan -> bucket starts
//   3. scatter composite keys (sortable_bits<<32)|idx into bucket ranges
//   4. BRANCH-FREE rank: prefetch all 8 (start,cap) pairs, then a fixed
//      6-deep predicated unroll counts same-bucket smaller keys. r8/r9/r11
//      showed divergent dynamic-trip LDS loops serialize on ds_read latency
//      (~20us); fixed-trip predication lets all reads pipeline.
//   5. u16 LDS staging (aliases dead hpos) + coalesced int4 emit w/ pad.
// Composite keys all-distinct; ties in t break by lower index == stable
// argsort == reference argmin semantics.
//
// mask (jnp.bool_) is uploaded by the harness as int32.
__global__ __launch_bounds__(THREADS) void time_greedy_rank_kernel(
    const float* __restrict__ time,
    const int* __restrict__ mask,             // int32: nonzero = excluded
    const int* __restrict__ pad_value_p,
    int* __restrict__ pred,                   // [B, L] int32
    int* __restrict__ valid_out)              // [B]    int32
{
    __shared__ uint64_t keys[LROW];      // 16 KB: scattered composite keys
    __shared__ uint32_t hstart[NBINS];   // 4 KB: exclusive bucket starts
    __shared__ uint32_t hpos[NBINS];     // 4 KB: counts->pos; REUSED as u16 oidx
    __shared__ uint32_t wsum[4];

    uint16_t* oidx = (uint16_t*)hpos;    // aliases hpos after scatter is done

    const int row = blockIdx.x;
    const int tid = threadIdx.x;
    const int lane = tid & 63;
    const int wid = tid >> 6;

    // ---- init hpos (stride-1) ----
#pragma unroll
    for (int e = 0; e < BPT; ++e) hpos[tid + e * THREADS] = 0;
    __syncthreads();

    // ---- vectorized load + histogram of valid elements ----
    const float4* trow4 = (const float4*)(time + (size_t)row * LROW);
    const int4*   mrow4 = (const int4*)(mask + (size_t)row * LROW);

    uint32_t ukey[8];
    int      bkt[8];
    int      mval[8];
#pragma unroll
    for (int c = 0; c < 2; ++c) {
        const int v = tid + c * THREADS;
        const float4 tq = trow4[v];
        const int4   mq = mrow4[v];
        const float tf[4] = {tq.x, tq.y, tq.z, tq.w};
        const int   mf[4] = {mq.x, mq.y, mq.z, mq.w};
#pragma unroll
        for (int j = 0; j < 4; ++j) {
            const int e = c * 4 + j;
            const uint32_t fb = __float_as_uint(tf[j]);
            // order-preserving float->uint transform (general form)
            ukey[e] = fb ^ ((uint32_t)((int32_t)fb >> 31) | 0x80000000u);
            int b = (int)(tf[j] * (float)NBINS);   // monotone value bucketing
            b = (b < 0) ? 0 : ((b > NBINS - 1) ? NBINS - 1 : b);
            bkt[e] = b;
            mval[e] = mf[j];
            if (!mf[j]) atomicAdd(&hpos[swz(b)], 1u);
        }
    }
    __syncthreads();

    // ---- exclusive prefix sum over 1024 bins (thread t owns bins 4t..4t+3) ----
    uint32_t h[BPT];
    uint32_t lsum = 0;
#pragma unroll
    for (int e = 0; e < BPT; ++e) {
        h[e] = hpos[e * THREADS + tid];   // stride-1
        lsum += h[e];
    }
    uint32_t incl = lsum;                 // wave-inclusive scan
#pragma unroll
    for (int off = 1; off < 64; off <<= 1) {
        const uint32_t y = __shfl_up(incl, off, 64);
        if (lane >= off) incl += y;
    }
    if (lane == 63) wsum[wid] = incl;
    __syncthreads();
    uint32_t woff = 0, total = 0;
#pragma unroll
    for (int w = 0; w < 4; ++w) {
        const uint32_t s = wsum[w];
        if (w < wid) woff += s;
        total += s;
    }
    uint32_t run = woff + incl - lsum;    // exclusive prefix for this thread's bins
#pragma unroll
    for (int e = 0; e < BPT; ++e) {
        hstart[e * THREADS + tid] = run;  // exclusive start (preserved)
        hpos[e * THREADS + tid] = run;    // running position for scatter
        run += h[e];
    }
    __syncthreads();

    // ---- scatter valid elements into their bucket ranges ----
#pragma unroll
    for (int c = 0; c < 2; ++c) {
#pragma unroll
        for (int j = 0; j < 4; ++j) {
            const int e = c * 4 + j;
            if (!mval[e]) {
                const int i = 4 * tid + c * (4 * THREADS) + j;  // element index
                const uint32_t pos = atomicAdd(&hpos[swz(bkt[e])], 1u);
                keys[pos] = ((uint64_t)ukey[e] << 32) | (uint32_t)i;
            }
        }
    }
    __syncthreads();
    // hpos now DEAD (bucket end b == hstart[b+1], or total for the last bin).
    // Its 4 KB are reused as the u16 rank-staging array oidx.

    const int vld = (int)total;

    // ---- prefetch all 8 (start, cap) pairs: 16 independent pipelined reads ----
    uint32_t sarr[8], cap[8];
#pragma unroll
    for (int e = 0; e < 8; ++e) {
        const int b = bkt[e];
        const uint32_t s = hstart[swz(b)];
        const uint32_t en = (b == NBINS - 1) ? (uint32_t)vld
                                             : hstart[swz(b + 1)];
        sarr[e] = s;
        cap[e] = mval[e] ? 0u : (en - s);   // cap=0 disables masked slots
    }

    // ---- branch-free fixed-unroll rank -> u16 LDS staging ----
#pragma unroll
    for (int e = 0; e < 8; ++e) {
        const int c = e >> 2, j = e & 3;
        const int i = 4 * tid + c * (4 * THREADS) + j;   // element index
        const uint64_t my = ((uint64_t)ukey[e] << 32) | (uint32_t)i;
        const uint32_t s = sarr[e], cz = cap[e];
        uint32_t rank = 0;
#pragma unroll
        for (uint32_t k = 0; k < RUNROLL; ++k) {
            if (k < cz) rank += (keys[s + k] < my) ? 1u : 0u;  // predicated
        }
        for (uint32_t k = RUNROLL; k < cz; ++k)               // rare tail
            rank += (keys[s + k] < my) ? 1u : 0u;
        if (cz) oidx[s + rank] = (uint16_t)i;   // self excluded by strict <
    }
    __syncthreads();

    // ---- coalesced int4 emit, pad folded in ----
    const int pad = pad_value_p[0];
    int4* prow4 = (int4*)(pred + (size_t)row * LROW);
#pragma unroll
    for (int c = 0; c < 2; ++c) {
        const int v = tid + c * THREADS;
        const int base = 4 * v;
        int4 o;                              // 8B/lane u16 reads: 2-way, free
        o.x = (base + 0 < vld) ? (int)oidx[base + 0] : pad;
        o.y = (base + 1 < vld) ? (int)oidx[base + 1] : pad;
        o.z = (base + 2 < vld) ? (int)oidx[base + 2] : pad;
        o.w = (base + 3 < vld) ? (int)oidx[base + 3] : pad;
        prow4[v] = o;                        // 1 KB/wave coalesced store
    }
    if (tid == 0) valid_out[row] = vld;
}

extern "C" void kernel_launch(void* const* d_in, const int* in_sizes, int n_in,
                              void* d_out, int out_size, void* d_ws, size_t ws_size,
                              hipStream_t stream) {
    const float* time = (const float*)d_in[0];
    const int* mask = (const int*)d_in[1];
    const int* pad_value = (const int*)d_in[2];

    const int B = in_sizes[0] / LROW;

    // d_out layout: pred [B*L] int32, then valid [B] int32 (tuple concat order)
    int* pred = (int*)d_out;
    int* valid_out = pred + (size_t)B * LROW;

    time_greedy_rank_kernel<<<B, THREADS, 0, stream>>>(time, mask, pad_value,
                                                       pred, valid_out);
}